// Round 2
// baseline (915.272 us; speedup 1.0000x reference)
//
#include <hip/hip_runtime.h>

#define D 128
#define MM_ROWS 32

// ---------------------------------------------------------------------------
// Kernel 0: zero the workspace (agg + deg + flag) — capture-safe by design.
// ---------------------------------------------------------------------------
__global__ void gs_zero(float4* __restrict__ p, int n4) {
    int i = blockIdx.x * blockDim.x + threadIdx.x;
    int stride = gridDim.x * blockDim.x;
    for (; i < n4; i += stride) p[i] = make_float4(0.f, 0.f, 0.f, 0.f);
}

// ---------------------------------------------------------------------------
// Kernel 1: detect whether edge_index arrived as int32 or int64.
// If int64 (little-endian, values < 2^31), every odd int32 word is 0.
// flag==1  => data is int32;  flag==0 => int64.
// ---------------------------------------------------------------------------
__global__ void gs_check_idx(const int* __restrict__ ei, int limit, int* __restrict__ flag) {
    int i = blockIdx.x * blockDim.x + threadIdx.x;
    if (i < limit && ei[2 * i + 1] != 0) atomicOr(flag, 1);
}

// ---------------------------------------------------------------------------
// Kernel 2: scatter-add  agg[tgt] += x[nbr],  deg[tgt] += 1
// One wave (64 lanes) per edge; lane handles 2 consecutive floats (512B/row).
// ---------------------------------------------------------------------------
__global__ __launch_bounds__(256) void gs_scatter(
    const int* __restrict__ ei, const float* __restrict__ x,
    float* __restrict__ agg, float* __restrict__ deg,
    const int* __restrict__ flag, int E, int n) {
    int e = blockIdx.x * 4 + (threadIdx.x >> 6);
    if (e >= E) return;
    int lane = threadIdx.x & 63;
    int tgt, nbr;
    if (*flag) {            // int32 layout: [tgt[0..E), nbr[0..E)]
        tgt = ei[e];
        nbr = ei[E + e];
    } else {                // int64 layout: low words at even positions
        tgt = ei[2 * e];
        nbr = ei[2 * (E + e)];
    }
    // safety: never write OOB even under dtype mis-detection
    if ((unsigned)tgt >= (unsigned)n || (unsigned)nbr >= (unsigned)n) return;
    const float2 v = *(const float2*)(x + (size_t)nbr * D + lane * 2);
    float* ar = agg + (size_t)tgt * D + lane * 2;
    unsafeAtomicAdd(ar, v.x);
    unsafeAtomicAdd(ar + 1, v.y);
    if (lane == 0) unsafeAtomicAdd(deg + tgt, 1.0f);
}

// ---------------------------------------------------------------------------
// Kernel 3: fused  out = normalize(relu(x@Wl + bl + (agg/deg)@Wr + br))
// Block: 256 threads, 32 rows. Thread = (colgroup cg in [0,32), rowgroup rg in
// [0,8)); computes a 4 rows x 4 cols fp32 tile. x/agg rows staged in LDS.
// ---------------------------------------------------------------------------
__global__ __launch_bounds__(256) void gs_fused(
    const float* __restrict__ x, const float* __restrict__ agg,
    const float* __restrict__ deg,
    const float* __restrict__ Wl, const float* __restrict__ bl,
    const float* __restrict__ Wr, const float* __restrict__ br,
    float* __restrict__ out, int n) {
    __shared__ float sx[MM_ROWS][D];
    __shared__ float sa[MM_ROWS][D];
    __shared__ float so[MM_ROWS][D];
    __shared__ float srdeg[MM_ROWS];
    __shared__ float snorm[MM_ROWS];

    const int tid = threadIdx.x;
    const int r0 = blockIdx.x * MM_ROWS;

    if (tid < MM_ROWS) {
        int r = r0 + tid;
        float dg = (r < n) ? deg[r] : 1.0f;
        srdeg[tid] = 1.0f / fmaxf(dg, 1.0f);
    }
    __syncthreads();

    // stage x and agg (scaled by 1/deg) rows: 32*128 floats each
    {
        const float4* xg = (const float4*)(x + (size_t)r0 * D);
        const float4* ag = (const float4*)(agg + (size_t)r0 * D);
        float4* sx4 = (float4*)&sx[0][0];
        float4* sa4 = (float4*)&sa[0][0];
#pragma unroll
        for (int it = 0; it < 4; ++it) {
            int idx = it * 256 + tid;     // float4 index; row = idx>>5
            int row = idx >> 5;
            if (r0 + row < n) {
                sx4[idx] = xg[idx];
                float4 a = ag[idx];
                float s = srdeg[row];
                a.x *= s; a.y *= s; a.z *= s; a.w *= s;
                sa4[idx] = a;
            } else {
                sx4[idx] = make_float4(0.f, 0.f, 0.f, 0.f);
                sa4[idx] = make_float4(0.f, 0.f, 0.f, 0.f);
            }
        }
    }
    __syncthreads();

    const int cg = tid & 31;       // column group: cols c0..c0+3
    const int rg = tid >> 5;       // row group:   rows rb..rb+3
    const int c0 = cg * 4;
    const int rb = rg * 4;

    float acc[4][4] = {};
#pragma unroll
    for (int k = 0; k < D; k += 4) {
        float4 xv[4], av[4];
#pragma unroll
        for (int r = 0; r < 4; ++r) {
            xv[r] = *(const float4*)&sx[rb + r][k];
            av[r] = *(const float4*)&sa[rb + r][k];
        }
#pragma unroll
        for (int kk = 0; kk < 4; ++kk) {
            const float4 wl = *(const float4*)(Wl + (size_t)(k + kk) * D + c0);
            const float4 wr = *(const float4*)(Wr + (size_t)(k + kk) * D + c0);
#pragma unroll
            for (int r = 0; r < 4; ++r) {
                float xs = (kk == 0) ? xv[r].x : (kk == 1) ? xv[r].y : (kk == 2) ? xv[r].z : xv[r].w;
                float as = (kk == 0) ? av[r].x : (kk == 1) ? av[r].y : (kk == 2) ? av[r].z : av[r].w;
                acc[r][0] += xs * wl.x; acc[r][0] += as * wr.x;
                acc[r][1] += xs * wl.y; acc[r][1] += as * wr.y;
                acc[r][2] += xs * wl.z; acc[r][2] += as * wr.z;
                acc[r][3] += xs * wl.w; acc[r][3] += as * wr.w;
            }
        }
    }

    // bias + relu -> so
    {
        const float4 blv = *(const float4*)(bl + c0);
        const float4 brv = *(const float4*)(br + c0);
        float bb[4] = {blv.x + brv.x, blv.y + brv.y, blv.z + brv.z, blv.w + brv.w};
#pragma unroll
        for (int r = 0; r < 4; ++r) {
            float4 o;
            o.x = fmaxf(acc[r][0] + bb[0], 0.f);
            o.y = fmaxf(acc[r][1] + bb[1], 0.f);
            o.z = fmaxf(acc[r][2] + bb[2], 0.f);
            o.w = fmaxf(acc[r][3] + bb[3], 0.f);
            *(float4*)&so[rb + r][c0] = o;
        }
    }
    __syncthreads();

    // row L2 norms: wave w handles rows w*8 .. w*8+7
    {
        const int wave = tid >> 6, lane = tid & 63;
#pragma unroll
        for (int it = 0; it < 8; ++it) {
            int row = wave * 8 + it;
            float2 v = *(const float2*)&so[row][lane * 2];
            float s = v.x * v.x + v.y * v.y;
#pragma unroll
            for (int off = 32; off > 0; off >>= 1) s += __shfl_down(s, off, 64);
            if (lane == 0) snorm[row] = 1.0f / (sqrtf(s) + 1e-6f);
        }
    }
    __syncthreads();

    // normalized coalesced store
#pragma unroll
    for (int it = 0; it < 16; ++it) {
        int idx = it * 256 + tid;    // element within tile
        int row = idx >> 7;
        if (r0 + row < n) out[(size_t)r0 * D + idx] = so[row][idx & 127] * snorm[row];
    }
}

// ---------------------------------------------------------------------------
extern "C" void kernel_launch(void* const* d_in, const int* in_sizes, int n_in,
                              void* d_out, int out_size, void* d_ws, size_t ws_size,
                              hipStream_t stream) {
    const float* x  = (const float*)d_in[0];
    const int*   ei = (const int*)d_in[1];
    const float* Wl = (const float*)d_in[2];
    const float* bl = (const float*)d_in[3];
    const float* Wr = (const float*)d_in[4];
    const float* br = (const float*)d_in[5];
    float* out = (float*)d_out;

    const int n = in_sizes[0] / D;
    const int E = in_sizes[1] / 2;

    float* agg  = (float*)d_ws;
    float* deg  = agg + (size_t)n * D;
    int*   flag = (int*)(deg + n);

    // zero agg + deg + flag:  (n*D + n + 4) floats, divisible by 4
    const int n4 = (n * D + n + 4) / 4;
    gs_zero<<<2048, 256, 0, stream>>>((float4*)d_ws, n4);

    int limit = E < 2048 ? E : 2048;
    gs_check_idx<<<(limit + 255) / 256, 256, 0, stream>>>(ei, limit, flag);
    gs_scatter<<<(E + 3) / 4, 256, 0, stream>>>(ei, x, agg, deg, flag, E, n);
    gs_fused<<<(n + MM_ROWS - 1) / MM_ROWS, 256, 0, stream>>>(x, agg, deg, Wl, bl, Wr, br, out, n);
}

// Round 3
// 401.659 us; speedup vs baseline: 2.2787x; 2.2787x over previous
//
#include <hip/hip_runtime.h>

#define D 128
#define MM_ROWS 32

// ---------------------------------------------------------------------------
// Kernel 0: zero counts+cursor+flag (2n+4 ints). agg no longer needs zeroing:
// gs_agg writes every row.
// ---------------------------------------------------------------------------
__global__ void gs_zero_i(int* __restrict__ p, int n) {
    int i = blockIdx.x * blockDim.x + threadIdx.x;
    int st = gridDim.x * blockDim.x;
    for (; i < n; i += st) p[i] = 0;
}

// ---------------------------------------------------------------------------
// Kernel 1: detect int32 vs int64 edge_index. flag==1 => int32, 0 => int64.
// ---------------------------------------------------------------------------
__global__ void gs_check_idx(const int* __restrict__ ei, int limit, int* __restrict__ flag) {
    int i = blockIdx.x * blockDim.x + threadIdx.x;
    if (i < limit && ei[2 * i + 1] != 0) atomicOr(flag, 1);
}

// ---------------------------------------------------------------------------
// Kernel 2: histogram of targets.
// ---------------------------------------------------------------------------
__global__ void gs_hist(const int* __restrict__ ei, int* __restrict__ counts,
                        const int* __restrict__ flag, int E, int n) {
    int e = blockIdx.x * blockDim.x + threadIdx.x;
    if (e >= E) return;
    int tgt = (*flag) ? ei[e] : ei[2 * e];
    if ((unsigned)tgt < (unsigned)n) atomicAdd(&counts[tgt], 1);
}

// ---------------------------------------------------------------------------
// Kernel 3a: per-block (256-wide) exclusive scan of counts -> offs,
// block sums -> partials[b].
// ---------------------------------------------------------------------------
__global__ __launch_bounds__(256) void gs_scanA(const int* __restrict__ counts,
                                                int* __restrict__ offs,
                                                int* __restrict__ partials, int n) {
    __shared__ int s[256];
    const int tid = threadIdx.x;
    const int i = blockIdx.x * 256 + tid;
    int v = (i < n) ? counts[i] : 0;
    s[tid] = v;
    __syncthreads();
    for (int off = 1; off < 256; off <<= 1) {
        int t = (tid >= off) ? s[tid - off] : 0;
        __syncthreads();
        s[tid] += t;
        __syncthreads();
    }
    if (i < n) offs[i] = s[tid] - v;               // exclusive
    if (tid == 255) partials[blockIdx.x] = s[255]; // block total
}

// ---------------------------------------------------------------------------
// Kernel 3b: exclusive scan of block partials (nb <= 512) in one block.
// ---------------------------------------------------------------------------
__global__ __launch_bounds__(512) void gs_scanB(int* __restrict__ partials, int nb) {
    __shared__ int s[512];
    const int tid = threadIdx.x;
    int v = (tid < nb) ? partials[tid] : 0;
    s[tid] = v;
    __syncthreads();
    for (int off = 1; off < 512; off <<= 1) {
        int t = (tid >= off) ? s[tid - off] : 0;
        __syncthreads();
        s[tid] += t;
        __syncthreads();
    }
    if (tid < nb) partials[tid] = s[tid] - v;      // exclusive
}

// ---------------------------------------------------------------------------
// Kernel 4: bin neighbors into CSR slots. Segment base = offs + partials.
// ---------------------------------------------------------------------------
__global__ void gs_bin(const int* __restrict__ ei, const int* __restrict__ offs,
                       const int* __restrict__ partials, int* __restrict__ cursor,
                       int* __restrict__ sorted_nbr, const int* __restrict__ flag,
                       int E, int n) {
    int e = blockIdx.x * blockDim.x + threadIdx.x;
    if (e >= E) return;
    int tgt, nbr;
    if (*flag) { tgt = ei[e];     nbr = ei[E + e]; }
    else       { tgt = ei[2 * e]; nbr = ei[2 * (E + e)]; }
    if ((unsigned)tgt >= (unsigned)n || (unsigned)nbr >= (unsigned)n) return;
    int p = offs[tgt] + partials[tgt >> 8] + atomicAdd(&cursor[tgt], 1);
    sorted_nbr[p] = nbr;
}

// ---------------------------------------------------------------------------
// Kernel 5: segmented mean. One wave per node; lane owns 2 floats of the row.
// Writes agg pre-divided by max(deg,1) (zero rows stay zero).
// ---------------------------------------------------------------------------
__global__ __launch_bounds__(256) void gs_agg(
    const int* __restrict__ sorted_nbr, const int* __restrict__ counts,
    const int* __restrict__ offs, const int* __restrict__ partials,
    const float* __restrict__ x, float* __restrict__ agg, int n) {
    int node = blockIdx.x * 4 + (threadIdx.x >> 6);
    if (node >= n) return;
    const int lane = threadIdx.x & 63;
    const int cnt = counts[node];
    const int start = offs[node] + partials[node >> 8];
    float ax = 0.f, ay = 0.f;
    for (int j = 0; j < cnt; ++j) {
        int nbr = sorted_nbr[start + j];
        const float2 v = *(const float2*)(x + (size_t)nbr * D + lane * 2);
        ax += v.x; ay += v.y;
    }
    const float inv = (cnt > 0) ? (1.0f / (float)cnt) : 0.0f;
    *(float2*)(agg + (size_t)node * D + lane * 2) = make_float2(ax * inv, ay * inv);
}

// ---------------------------------------------------------------------------
// Kernel 6: fused  out = normalize(relu(x@Wl + bl + agg@Wr + br))
// agg is already the mean. 256 threads, 32 rows, 4x4 fp32 tile per thread.
// ---------------------------------------------------------------------------
__global__ __launch_bounds__(256) void gs_fused(
    const float* __restrict__ x, const float* __restrict__ agg,
    const float* __restrict__ Wl, const float* __restrict__ bl,
    const float* __restrict__ Wr, const float* __restrict__ br,
    float* __restrict__ out, int n) {
    __shared__ float sx[MM_ROWS][D];
    __shared__ float sa[MM_ROWS][D];
    __shared__ float so[MM_ROWS][D];
    __shared__ float snorm[MM_ROWS];

    const int tid = threadIdx.x;
    const int r0 = blockIdx.x * MM_ROWS;

    // stage x and agg rows: 32*128 floats each
    {
        const float4* xg = (const float4*)(x + (size_t)r0 * D);
        const float4* ag = (const float4*)(agg + (size_t)r0 * D);
        float4* sx4 = (float4*)&sx[0][0];
        float4* sa4 = (float4*)&sa[0][0];
#pragma unroll
        for (int it = 0; it < 4; ++it) {
            int idx = it * 256 + tid;     // float4 index; row = idx>>5
            int row = idx >> 5;
            if (r0 + row < n) {
                sx4[idx] = xg[idx];
                sa4[idx] = ag[idx];
            } else {
                sx4[idx] = make_float4(0.f, 0.f, 0.f, 0.f);
                sa4[idx] = make_float4(0.f, 0.f, 0.f, 0.f);
            }
        }
    }
    __syncthreads();

    const int cg = tid & 31;       // column group: cols c0..c0+3
    const int rg = tid >> 5;       // row group:   rows rb..rb+3
    const int c0 = cg * 4;
    const int rb = rg * 4;

    float acc[4][4] = {};
#pragma unroll
    for (int k = 0; k < D; k += 4) {
        float4 xv[4], av[4];
#pragma unroll
        for (int r = 0; r < 4; ++r) {
            xv[r] = *(const float4*)&sx[rb + r][k];
            av[r] = *(const float4*)&sa[rb + r][k];
        }
#pragma unroll
        for (int kk = 0; kk < 4; ++kk) {
            const float4 wl = *(const float4*)(Wl + (size_t)(k + kk) * D + c0);
            const float4 wr = *(const float4*)(Wr + (size_t)(k + kk) * D + c0);
#pragma unroll
            for (int r = 0; r < 4; ++r) {
                float xs = (kk == 0) ? xv[r].x : (kk == 1) ? xv[r].y : (kk == 2) ? xv[r].z : xv[r].w;
                float as = (kk == 0) ? av[r].x : (kk == 1) ? av[r].y : (kk == 2) ? av[r].z : av[r].w;
                acc[r][0] += xs * wl.x; acc[r][0] += as * wr.x;
                acc[r][1] += xs * wl.y; acc[r][1] += as * wr.y;
                acc[r][2] += xs * wl.z; acc[r][2] += as * wr.z;
                acc[r][3] += xs * wl.w; acc[r][3] += as * wr.w;
            }
        }
    }

    // bias + relu -> so
    {
        const float4 blv = *(const float4*)(bl + c0);
        const float4 brv = *(const float4*)(br + c0);
        float bb[4] = {blv.x + brv.x, blv.y + brv.y, blv.z + brv.z, blv.w + brv.w};
#pragma unroll
        for (int r = 0; r < 4; ++r) {
            float4 o;
            o.x = fmaxf(acc[r][0] + bb[0], 0.f);
            o.y = fmaxf(acc[r][1] + bb[1], 0.f);
            o.z = fmaxf(acc[r][2] + bb[2], 0.f);
            o.w = fmaxf(acc[r][3] + bb[3], 0.f);
            *(float4*)&so[rb + r][c0] = o;
        }
    }
    __syncthreads();

    // row L2 norms: wave w handles rows w*8 .. w*8+7
    {
        const int wave = tid >> 6, lane = tid & 63;
#pragma unroll
        for (int it = 0; it < 8; ++it) {
            int row = wave * 8 + it;
            float2 v = *(const float2*)&so[row][lane * 2];
            float s = v.x * v.x + v.y * v.y;
#pragma unroll
            for (int off = 32; off > 0; off >>= 1) s += __shfl_down(s, off, 64);
            if (lane == 0) snorm[row] = 1.0f / (sqrtf(s) + 1e-6f);
        }
    }
    __syncthreads();

    // normalized coalesced store
#pragma unroll
    for (int it = 0; it < 16; ++it) {
        int idx = it * 256 + tid;    // element within tile
        int row = idx >> 7;
        if (r0 + row < n) out[(size_t)r0 * D + idx] = so[row][idx & 127] * snorm[row];
    }
}

// ---------------------------------------------------------------------------
extern "C" void kernel_launch(void* const* d_in, const int* in_sizes, int n_in,
                              void* d_out, int out_size, void* d_ws, size_t ws_size,
                              hipStream_t stream) {
    const float* x  = (const float*)d_in[0];
    const int*   ei = (const int*)d_in[1];
    const float* Wl = (const float*)d_in[2];
    const float* bl = (const float*)d_in[3];
    const float* Wr = (const float*)d_in[4];
    const float* br = (const float*)d_in[5];
    float* out = (float*)d_out;

    const int n = in_sizes[0] / D;
    const int E = in_sizes[1] / 2;
    const int nb = (n + 255) / 256;   // <= 512 for n <= 131072

    // workspace layout
    float* agg      = (float*)d_ws;                       // n*D floats
    int*   counts   = (int*)(agg + (size_t)n * D);        // n
    int*   cursor   = counts + n;                         // n
    int*   flag     = cursor + n;                         // 4 (pad)
    int*   offs     = flag + 4;                           // n
    int*   partials = offs + n;                           // 512
    int*   sorted   = partials + 512;                     // E

    gs_zero_i<<<512, 256, 0, stream>>>(counts, 2 * n + 4);   // counts+cursor+flag

    int limit = E < 2048 ? E : 2048;
    gs_check_idx<<<(limit + 255) / 256, 256, 0, stream>>>(ei, limit, flag);
    gs_hist<<<(E + 255) / 256, 256, 0, stream>>>(ei, counts, flag, E, n);
    gs_scanA<<<nb, 256, 0, stream>>>(counts, offs, partials, n);
    gs_scanB<<<1, 512, 0, stream>>>(partials, nb);
    gs_bin<<<(E + 255) / 256, 256, 0, stream>>>(ei, offs, partials, cursor, sorted, flag, E, n);
    gs_agg<<<(n + 3) / 4, 256, 0, stream>>>(sorted, counts, offs, partials, x, agg, n);
    gs_fused<<<(n + MM_ROWS - 1) / MM_ROWS, 256, 0, stream>>>(x, agg, Wl, bl, Wr, br, out, n);
}

// Round 4
// 267.824 us; speedup vs baseline: 3.4174x; 1.4997x over previous
//
#include <hip/hip_runtime.h>

#define D 128
#define BM 64

typedef __attribute__((ext_vector_type(8))) short bf16x8;
typedef __attribute__((ext_vector_type(4))) float f32x4;

// ---- bf16 helpers (hand-rolled, RNE) --------------------------------------
__device__ __forceinline__ float bf2f(unsigned short u) {
    union { unsigned int i; float f; } v; v.i = ((unsigned int)u) << 16; return v.f;
}
__device__ __forceinline__ unsigned short f2bf(float f) {
    union { float f; unsigned int i; } v; v.f = f;
    unsigned int x = v.i;
    unsigned int r = (x + 0x7fffu + ((x >> 16) & 1u)) >> 16;   // RNE
    return (unsigned short)r;
}

// ---------------------------------------------------------------------------
// Kernel 1: prep — detect idx dtype, zero counts+cursor, convert x -> x_bf,
// pack weights into MFMA-B-fragment order (B_packed).
// B layout: chunk q in [0,4096): g=q&3, c=(q>>2)&127, s=q>>9;
//   B_packed[q*8+j] = W[k= s*32+g*8+j][c]   (W = Wl for k<128 else Wr)
// ---------------------------------------------------------------------------
__global__ __launch_bounds__(256) void gs_prep(
    const float* __restrict__ x, const float* __restrict__ Wl,
    const float* __restrict__ Wr, const int* __restrict__ ei,
    unsigned short* __restrict__ x_bf, unsigned short* __restrict__ Bp,
    int* __restrict__ counts, int* __restrict__ flag, int n, int E) {
    const int tid0 = blockIdx.x * 256 + threadIdx.x;
    const int stride = gridDim.x * 256;

    // idx dtype detect: first wave of block 0 (no pre-zero needed)
    if (blockIdx.x == 0 && threadIdx.x < 64) {
        int lim = (E < 64) ? E : 64;
        int odd = (threadIdx.x < lim) ? ei[2 * threadIdx.x + 1] : 0;
        unsigned long long b = __ballot(odd != 0);
        if (threadIdx.x == 0) *flag = (b != 0ULL) ? 1 : 0;
    }
    // zero counts + cursor (2n ints)
    for (int i = tid0; i < 2 * n; i += stride) counts[i] = 0;
    // convert x -> bf16, 8 elems per thread-iter
    const int nch = n * (D / 8);
    for (int i = tid0; i < nch; i += stride) {
        const float4 a = *(const float4*)(x + (size_t)i * 8);
        const float4 b = *(const float4*)(x + (size_t)i * 8 + 4);
        unsigned short o[8] = {f2bf(a.x), f2bf(a.y), f2bf(a.z), f2bf(a.w),
                               f2bf(b.x), f2bf(b.y), f2bf(b.z), f2bf(b.w)};
        *(uint4*)(x_bf + (size_t)i * 8) = *(const uint4*)o;
    }
    // pack weights (4096 chunks)
    for (int q = tid0; q < 4096; q += stride) {
        int g = q & 3, c = (q >> 2) & 127, s = q >> 9;
        unsigned short o[8];
#pragma unroll
        for (int j = 0; j < 8; ++j) {
            int k = s * 32 + g * 8 + j;
            float w = (k < 128) ? Wl[k * 128 + c] : Wr[(k - 128) * 128 + c];
            o[j] = f2bf(w);
        }
        *(uint4*)(Bp + (size_t)q * 8) = *(const uint4*)o;
    }
}

// ---------------------------------------------------------------------------
// Kernel 2: histogram of targets.
// ---------------------------------------------------------------------------
__global__ void gs_hist(const int* __restrict__ ei, int* __restrict__ counts,
                        const int* __restrict__ flag, int E, int n) {
    int e = blockIdx.x * blockDim.x + threadIdx.x;
    if (e >= E) return;
    int tgt = (*flag) ? ei[e] : ei[2 * e];
    if ((unsigned)tgt < (unsigned)n) atomicAdd(&counts[tgt], 1);
}

// ---------------------------------------------------------------------------
// Kernel 3a/3b: two-level exclusive scan.
// ---------------------------------------------------------------------------
__global__ __launch_bounds__(256) void gs_scanA(const int* __restrict__ counts,
                                                int* __restrict__ offs,
                                                int* __restrict__ partials, int n) {
    __shared__ int s[256];
    const int tid = threadIdx.x;
    const int i = blockIdx.x * 256 + tid;
    int v = (i < n) ? counts[i] : 0;
    s[tid] = v;
    __syncthreads();
    for (int off = 1; off < 256; off <<= 1) {
        int t = (tid >= off) ? s[tid - off] : 0;
        __syncthreads();
        s[tid] += t;
        __syncthreads();
    }
    if (i < n) offs[i] = s[tid] - v;
    if (tid == 255) partials[blockIdx.x] = s[255];
}

__global__ __launch_bounds__(512) void gs_scanB(int* __restrict__ partials, int nb) {
    __shared__ int s[512];
    const int tid = threadIdx.x;
    int v = (tid < nb) ? partials[tid] : 0;
    s[tid] = v;
    __syncthreads();
    for (int off = 1; off < 512; off <<= 1) {
        int t = (tid >= off) ? s[tid - off] : 0;
        __syncthreads();
        s[tid] += t;
        __syncthreads();
    }
    if (tid < nb) partials[tid] = s[tid] - v;
}

// ---------------------------------------------------------------------------
// Kernel 4: bin neighbors into CSR slots.
// ---------------------------------------------------------------------------
__global__ void gs_bin(const int* __restrict__ ei, const int* __restrict__ offs,
                       const int* __restrict__ partials, int* __restrict__ cursor,
                       int* __restrict__ sorted_nbr, const int* __restrict__ flag,
                       int E, int n) {
    int e = blockIdx.x * blockDim.x + threadIdx.x;
    if (e >= E) return;
    int tgt, nbr;
    if (*flag) { tgt = ei[e];     nbr = ei[E + e]; }
    else       { tgt = ei[2 * e]; nbr = ei[2 * (E + e)]; }
    if ((unsigned)tgt >= (unsigned)n || (unsigned)nbr >= (unsigned)n) return;
    int p = offs[tgt] + partials[tgt >> 8] + atomicAdd(&cursor[tgt], 1);
    sorted_nbr[p] = nbr;
}

// ---------------------------------------------------------------------------
// Kernel 5: segmented mean over bf16 x. One wave per node; quarter-wave per
// neighbor row (4 rows/iter); lane reads 16B (8 bf16). fp32 accumulate,
// bf16 mean output (pre-divided).
// ---------------------------------------------------------------------------
__global__ __launch_bounds__(256) void gs_agg(
    const int* __restrict__ sorted_nbr, const int* __restrict__ counts,
    const int* __restrict__ offs, const int* __restrict__ partials,
    const unsigned short* __restrict__ x_bf, unsigned short* __restrict__ agg_bf,
    int n) {
    int node = blockIdx.x * 4 + (threadIdx.x >> 6);
    if (node >= n) return;
    const int lane = threadIdx.x & 63;
    const int qw = lane >> 4, c = lane & 15;
    const int cnt = counts[node];
    const int start = offs[node] + partials[node >> 8];
    float a[8] = {};
    for (int j = 0; j < cnt; j += 4) {
        int jj = j + qw;
        if (jj < cnt) {
            int nbr = sorted_nbr[start + jj];
            uint4 raw = *(const uint4*)(x_bf + (size_t)nbr * D + c * 8);
            const unsigned short* u = (const unsigned short*)&raw;
#pragma unroll
            for (int e = 0; e < 8; ++e) a[e] += bf2f(u[e]);
        }
    }
#pragma unroll
    for (int e = 0; e < 8; ++e) {
        a[e] += __shfl_xor(a[e], 16, 64);
        a[e] += __shfl_xor(a[e], 32, 64);
    }
    if (qw == 0) {
        const float inv = (cnt > 0) ? (1.0f / (float)cnt) : 0.0f;
        unsigned short o[8];
#pragma unroll
        for (int e = 0; e < 8; ++e) o[e] = f2bf(a[e] * inv);
        *(uint4*)(agg_bf + (size_t)node * D + c * 8) = *(const uint4*)o;
    }
}

// ---------------------------------------------------------------------------
// Kernel 6: fused MFMA GEMM  out = normalize(relu([x|agg] @ [Wl;Wr] + bl+br))
// M-tile 64 rows, 4 waves; wave w owns rows w*16..w*16+15, all 128 cols.
// K = 256 = 8 steps of 32. A staged in LDS (XOR-swizzled 16B chunks);
// B frags loaded from pre-packed global (L2-hot, coalesced dwordx4).
// Frag maps: A row=l&15,k=(l>>4)*8+j; B k=(l>>4)*8+j,col=l&15;
//            C/D col=l&15,row=(l>>4)*4+r (m89-verified).
// ---------------------------------------------------------------------------
__global__ __launch_bounds__(256) void gs_fused(
    const unsigned short* __restrict__ x_bf, const unsigned short* __restrict__ agg_bf,
    const unsigned short* __restrict__ Bp,
    const float* __restrict__ bl, const float* __restrict__ br,
    float* __restrict__ out, int n) {
    __shared__ unsigned short sA[BM][256];   // 32 KB

    const int tid = threadIdx.x;
    const int wave = tid >> 6, lane = tid & 63;
    const int g = lane >> 4, c = lane & 15;
    const int r0 = blockIdx.x * BM;

    // stage A: 64 rows x 32 chunks(16B). chunk<16 from x_bf, else agg_bf.
#pragma unroll
    for (int it = 0; it < 8; ++it) {
        int idx = it * 256 + tid;
        int row = idx >> 5, ch = idx & 31;
        int grow = r0 + row;
        uint4 val = make_uint4(0u, 0u, 0u, 0u);
        if (grow < n) {
            const unsigned short* src = (ch < 16)
                ? (x_bf + (size_t)grow * D + ch * 8)
                : (agg_bf + (size_t)grow * D + (ch - 16) * 8);
            val = *(const uint4*)src;
        }
        int sch = ch ^ (row & 7);
        *(uint4*)((char*)&sA[0][0] + row * 512 + sch * 16) = val;
    }
    __syncthreads();

    f32x4 acc[8] = {};
    const int arow = wave * 16 + c;          // A-operand row for this lane
    const int axor = (arow & 7);
#pragma unroll
    for (int s = 0; s < 8; ++s) {
        bf16x8 afrag = *(const bf16x8*)((const char*)&sA[0][0] +
                                        arow * 512 + (((s * 4 + g) ^ axor) * 16));
#pragma unroll
        for (int f = 0; f < 8; ++f) {
            bf16x8 bfrag = *(const bf16x8*)(Bp + (size_t)(((s * 128 + f * 16 + c) * 4 + g) * 8));
            acc[f] = __builtin_amdgcn_mfma_f32_16x16x32_bf16(afrag, bfrag, acc[f], 0, 0, 0);
        }
    }

    // epilogue: bias + relu, row sumsq via 16-lane shfl_xor, normalize, store
    float v[8][4];
    float sumsq[4] = {0.f, 0.f, 0.f, 0.f};
#pragma unroll
    for (int f = 0; f < 8; ++f) {
        float bb = bl[f * 16 + c] + br[f * 16 + c];
#pragma unroll
        for (int r = 0; r < 4; ++r) {
            float y = fmaxf(acc[f][r] + bb, 0.f);
            v[f][r] = y;
            sumsq[r] += y * y;
        }
    }
#pragma unroll
    for (int r = 0; r < 4; ++r) {
        float s = sumsq[r];
        s += __shfl_xor(s, 1, 64);
        s += __shfl_xor(s, 2, 64);
        s += __shfl_xor(s, 4, 64);
        s += __shfl_xor(s, 8, 64);
        sumsq[r] = 1.0f / (sqrtf(s) + 1e-6f);
    }
    const int baserow = r0 + wave * 16 + g * 4;
#pragma unroll
    for (int r = 0; r < 4; ++r) {
        int row = baserow + r;
        if (row < n) {
#pragma unroll
            for (int f = 0; f < 8; ++f)
                out[(size_t)row * D + f * 16 + c] = v[f][r] * sumsq[r];
        }
    }
}

// ---------------------------------------------------------------------------
extern "C" void kernel_launch(void* const* d_in, const int* in_sizes, int n_in,
                              void* d_out, int out_size, void* d_ws, size_t ws_size,
                              hipStream_t stream) {
    const float* x  = (const float*)d_in[0];
    const int*   ei = (const int*)d_in[1];
    const float* Wl = (const float*)d_in[2];
    const float* bl = (const float*)d_in[3];
    const float* Wr = (const float*)d_in[4];
    const float* br = (const float*)d_in[5];
    float* out = (float*)d_out;

    const int n = in_sizes[0] / D;
    const int E = in_sizes[1] / 2;
    const int nb = (n + 255) / 256;          // 391 for n=100000 (<=512)

    // workspace layout (16B-aligned sections)
    unsigned short* x_bf   = (unsigned short*)d_ws;                 // n*128
    unsigned short* agg_bf = x_bf + (size_t)n * D;                  // n*128
    unsigned short* Bp     = agg_bf + (size_t)n * D;                // 32768
    int*   counts   = (int*)(Bp + 32768);                           // n
    int*   cursor   = counts + n;                                   // n
    int*   flag     = cursor + n;                                   // 4 pad
    int*   offs     = flag + 4;                                     // n
    int*   partials = offs + n;                                     // 512
    int*   sorted   = partials + 512;                               // E

    gs_prep<<<4096, 256, 0, stream>>>(x, Wl, Wr, ei, x_bf, Bp, counts, flag, n, E);
    gs_hist<<<(E + 255) / 256, 256, 0, stream>>>(ei, counts, flag, E, n);
    gs_scanA<<<nb, 256, 0, stream>>>(counts, offs, partials, n);
    gs_scanB<<<1, 512, 0, stream>>>(partials, nb);
    gs_bin<<<(E + 255) / 256, 256, 0, stream>>>(ei, offs, partials, cursor, sorted, flag, E, n);
    gs_agg<<<(n + 3) / 4, 256, 0, stream>>>(sorted, counts, offs, partials, x_bf, agg_bf, n);
    gs_fused<<<(n + BM - 1) / BM, 256, 0, stream>>>(x_bf, agg_bf, Bp, bl, br, out, n);
}